// Round 4
// baseline (888.733 us; speedup 1.0000x reference)
//
#include <hip/hip_runtime.h>
#include <cstddef>

constexpr int V_CNT = 65536;
constexpr int E_CNT = 1048576;
constexpr int H_DIM = 128;
constexpr int CI = 34;   // chem in
constexpr int GI = 48;   // geom in
#define EPSF 1e-5f

typedef _Float16 f16;
typedef f16 f16x8 __attribute__((ext_vector_type(8)));
typedef float f32x4 __attribute__((ext_vector_type(4)));
#define MFMA16(a,b,c) __builtin_amdgcn_mfma_f32_16x16x32_f16(a,b,c,0,0,0)

// fast rcp: single v_rcp_f32 (~1ulp) instead of IEEE div sequence
__device__ __forceinline__ float frcp_(float x){ return __builtin_amdgcn_rcpf(x); }
__device__ __forceinline__ float sigmoidf_(float x){ return frcp_(1.0f+__expf(-x)); }
__device__ __forceinline__ float siluf_(float x){ return x*frcp_(1.0f+__expf(-x)); }
__device__ __forceinline__ float softplusf_(float x){
  return fmaxf(x,0.0f) + __logf(1.0f + __expf(-fabsf(x)));
}

// ---------------- FRONT: prep (blocks 0..127) + hist (blocks 128..1151) + zero h_chem (1152..3199)
__global__ __launch_bounds__(256) void front_kernel(
    const float* __restrict__ w1, const float* __restrict__ b1, const float* __restrict__ bn1,
    const float* __restrict__ w2, const float* __restrict__ b2, const float* __restrict__ bn2,
    const float* __restrict__ wg1, const float* __restrict__ bg1, const float* __restrict__ bng1,
    const float* __restrict__ wg2, const float* __restrict__ bg2, const float* __restrict__ bng2,
    const float* __restrict__ wf1, const float* __restrict__ bf1, const float* __restrict__ bnf1,
    const float* __restrict__ wf2, const float* __restrict__ bf2, const float* __restrict__ bnf2,
    f16* __restrict__ w1f, float* __restrict__ shift1,
    f16* __restrict__ w2f, float* __restrict__ shift2,
    f16* __restrict__ wg1f, float* __restrict__ shiftg1,
    f16* __restrict__ wg2f, float* __restrict__ shiftg2,
    f16* __restrict__ wf1f, float* __restrict__ shiftf1,
    f16* __restrict__ wf2f, float* __restrict__ shiftf2,
    const int* __restrict__ vids, int* __restrict__ counts,
    float4* __restrict__ h_chem_zero)
{
  const int b = blockIdx.x;
  if (b >= 1152) {                      // zero h_chem: 2048 blocks
    int i = (b-1152)*256 + threadIdx.x;
    float4 z; z.x=0.f; z.y=0.f; z.z=0.f; z.w=0.f;
    const int n4 = V_CNT*H_DIM/4;
    for(; i<n4; i+=2048*256) h_chem_zero[i] = z;
    return;
  }
  if (b >= 128) {                       // hist: 1024 blocks
    int i = (b-128)*256 + threadIdx.x;
    for(; i<E_CNT; i+=1024*256) atomicAdd(&counts[vids[i]], 1);
    return;
  }
  int t = b*256 + threadIdx.x;
  if (t < 128*64){                       // chem L1: [128 cols][64 k], k>=34 zero
    int n = t>>6, k = t&63;
    float s = bn1[n]*rsqrtf(bn1[384+n]+EPSF);
    w1f[t] = (k<CI) ? (f16)(w1[k*128+n]*s) : (f16)0.f;
    if (k==0) shift1[n] = fmaf(s, b1[n]-bn1[256+n], bn1[128+n]);
  }
  if (t < 256*128){                      // chem L2: [256 cols][128 k]
    int n = t>>7, k = t&127;
    float s = bn2[n]*rsqrtf(bn2[768+n]+EPSF);
    w2f[t] = (f16)(w2[k*256+n]*s);
    if (k==0) shift2[n] = fmaf(s, b2[n]-bn2[512+n], bn2[256+n]);
  }
  if (t < 64*64){                        // geom L1: [64 cols][64 k], k>=48 zero
    int n = t>>6, k = t&63;
    float s = bng1[n]*rsqrtf(bng1[192+n]+EPSF);
    wg1f[t] = (k<GI) ? (f16)(wg1[k*64+n]*s) : (f16)0.f;
    if (k==0) shiftg1[n] = fmaf(s, bg1[n]-bng1[128+n], bng1[64+n]);
  }
  if (t < 64*64){                        // geom L2: [64 cols][64 k]
    int n = t>>6, k = t&63;
    float s = bng2[n]*rsqrtf(bng2[192+n]+EPSF);
    wg2f[t] = (f16)(wg2[k*64+n]*s);
    if (k==0) shiftg2[n] = fmaf(s, bg2[n]-bng2[128+n], bng2[64+n]);
  }
  if (t < 128*192){                      // feat L1: [128 cols][192 k]
    int n = t/192, k = t - n*192;
    float s = bnf1[n]*rsqrtf(bnf1[384+n]+EPSF);
    wf1f[t] = (f16)(wf1[k*128+n]*s);
    if (k==0) shiftf1[n] = fmaf(s, bf1[n]-bnf1[256+n], bnf1[128+n]);
  }
  if (t < 128*128){                      // feat L2: [128 cols][128 k]
    int n = t>>7, k = t&127;
    float s = bnf2[n]*rsqrtf(bnf2[384+n]+EPSF);
    wf2f[t] = (f16)(wf2[k*128+n]*s);
    if (k==0) shiftf2[n] = fmaf(s, bf2[n]-bnf2[256+n], bnf2[128+n]);
  }
}

__global__ __launch_bounds__(1024) void scan_kernel(const int* __restrict__ counts,
                                                    int* __restrict__ offsets_work){
  __shared__ int ps[1024];
  const int t = threadIdx.x;
  int4 c[16]; int s = 0;
  const int4* cp = (const int4*)counts + (size_t)t*16;
  #pragma unroll
  for(int i=0;i<16;i++){ c[i]=cp[i]; s += c[i].x+c[i].y+c[i].z+c[i].w; }
  ps[t]=s; __syncthreads();
  for(int d=1; d<1024; d<<=1){
    int v = (t>=d) ? ps[t-d] : 0;
    __syncthreads();
    ps[t] += v;
    __syncthreads();
  }
  int run = ps[t]-s;
  int4* o2 = (int4*)offsets_work + (size_t)t*16;
  #pragma unroll
  for(int i=0;i<16;i++){
    int4 cc=c[i]; int4 o;
    o.x=run; run+=cc.x; o.y=run; run+=cc.y; o.z=run; run+=cc.z; o.w=run; run+=cc.w;
    o2[i]=o;
  }
}

// scatter materializes perm AND svid (sorted vids), avoiding a dependent random gather later
__global__ __launch_bounds__(256) void scatter_kernel(const int* __restrict__ vids,
                                                      int* __restrict__ offsets_work,
                                                      int* __restrict__ perm,
                                                      int* __restrict__ svid){
  int i = blockIdx.x*blockDim.x + threadIdx.x;
  int stride = gridDim.x*blockDim.x;
  for(; i<E_CNT; i+=stride){
    int v = vids[i];
    int pos = atomicAdd(&offsets_work[v], 1);
    perm[pos] = i;
    svid[pos] = v;
  }
}

// ---------------- geom MLP via MFMA (fallback path only)
__global__ __launch_bounds__(256) void geom_mfma(
    const float* __restrict__ geom,
    const f16* __restrict__ wg1f, const float* __restrict__ shg1,
    const f16* __restrict__ wg2f, const float* __restrict__ shg2,
    f16* __restrict__ dst)
{
  __shared__ __align__(16) f16 Ag[64][72];
  const int t = threadIdx.x, w = t>>6, lane = t&63, n16 = lane&15, quad = lane>>4;
  const int v0 = blockIdx.x*64;
  const int col = w*16 + n16;

  for(int i=t;i<64*GI;i+=256){ int r=i/GI, k=i-r*GI; Ag[r][k] = (f16)geom[(size_t)v0*GI + i]; }
  { uint* Aw=(uint*)Ag; for(int i=t;i<64*8;i+=256){ int r=i>>3; Aw[r*36+24+(i&7)]=0u; } }

  f16x8 bg1[2], bg2[2];
  #pragma unroll
  for(int ks=0;ks<2;ks++){
    bg1[ks] = *(const f16x8*)(wg1f + (size_t)col*64 + ks*32 + quad*8);
    bg2[ks] = *(const f16x8*)(wg2f + (size_t)col*64 + ks*32 + quad*8);
  }
  __syncthreads();

  f32x4 c1[4];
  #pragma unroll
  for(int mt=0;mt<4;mt++) c1[mt] = (f32x4)(0.f);
  #pragma unroll
  for(int mt=0;mt<4;mt++)
    #pragma unroll
    for(int ks=0;ks<2;ks++){
      f16x8 a = *(const f16x8*)(&Ag[mt*16+n16][ks*32+quad*8]);
      c1[mt] = MFMA16(a, bg1[ks], c1[mt]);
    }
  __syncthreads();

  float s1 = shg1[col];
  #pragma unroll
  for(int mt=0;mt<4;mt++)
    #pragma unroll
    for(int r=0;r<4;r++)
      Ag[mt*16+quad*4+r][col] = (f16)siluf_(c1[mt][r] + s1);
  __syncthreads();

  f32x4 c2[4];
  #pragma unroll
  for(int mt=0;mt<4;mt++) c2[mt] = (f32x4)(0.f);
  #pragma unroll
  for(int mt=0;mt<4;mt++)
    #pragma unroll
    for(int ks=0;ks<2;ks++){
      f16x8 a = *(const f16x8*)(&Ag[mt*16+n16][ks*32+quad*8]);
      c2[mt] = MFMA16(a, bg2[ks], c2[mt]);
    }
  float s2 = shg2[col];
  #pragma unroll
  for(int mt=0;mt<4;mt++)
    #pragma unroll
    for(int r=0;r<4;r++)
      dst[(size_t)(v0 + mt*16+quad*4+r)*64 + col] = (f16)(c2[mt][r] + s2);
}

// ---------------- CHEM+GEOM combined launch:
// blocks [0,1024): geom MLP; blocks [1024, 1024+8192): chem, 128 sorted edges/block.
// 128-edge tiles amortize per-block weight loads (w1f+w2f = 80KB L2 traffic per block)
// over 2x the edges, halve barrier count/edge, and lengthen segment runs per wave.
__global__ __launch_bounds__(256) void chem_geom(
    const float* __restrict__ chem, const float* __restrict__ geom,
    const int* __restrict__ perm, const int* __restrict__ svid,
    const f16* __restrict__ w1f, const float* __restrict__ shift1,
    const f16* __restrict__ w2f, const float* __restrict__ shift2,
    const f16* __restrict__ wg1f, const float* __restrict__ shg1,
    const f16* __restrict__ wg2f, const float* __restrict__ shg2,
    float* __restrict__ h_chem, f16* __restrict__ h_geom)
{
  __shared__ __align__(16) f16 A2[128][136];   // chem: L1 act then gated G; geom aliases [64][72]
  __shared__ int vid_s[128];
  const int t = threadIdx.x, w = t>>6, lane = t&63, n16 = lane&15, quad = lane>>4;

  if (blockIdx.x < 1024) {
    // ======== geom path ========
    f16 (*Ag)[72] = reinterpret_cast<f16(*)[72]>(&A2[0][0]);
    const int v0 = blockIdx.x*64;
    const int col = w*16 + n16;

    for(int i=t;i<64*GI;i+=256){ int r=i/GI, k=i-r*GI; Ag[r][k] = (f16)geom[(size_t)v0*GI + i]; }
    { uint* Aw=(uint*)&Ag[0][0]; for(int i=t;i<64*8;i+=256){ int r=i>>3; Aw[r*36+24+(i&7)]=0u; } }

    f16x8 bg1[2], bg2[2];
    #pragma unroll
    for(int ks=0;ks<2;ks++){
      bg1[ks] = *(const f16x8*)(wg1f + (size_t)col*64 + ks*32 + quad*8);
      bg2[ks] = *(const f16x8*)(wg2f + (size_t)col*64 + ks*32 + quad*8);
    }
    __syncthreads();

    f32x4 c1[4];
    #pragma unroll
    for(int mt=0;mt<4;mt++) c1[mt] = (f32x4)(0.f);
    #pragma unroll
    for(int mt=0;mt<4;mt++)
      #pragma unroll
      for(int ks=0;ks<2;ks++){
        f16x8 a = *(const f16x8*)(&Ag[mt*16+n16][ks*32+quad*8]);
        c1[mt] = MFMA16(a, bg1[ks], c1[mt]);
      }
    __syncthreads();

    float s1 = shg1[col];
    #pragma unroll
    for(int mt=0;mt<4;mt++)
      #pragma unroll
      for(int r=0;r<4;r++)
        Ag[mt*16+quad*4+r][col] = (f16)siluf_(c1[mt][r] + s1);
    __syncthreads();

    f32x4 c2[4];
    #pragma unroll
    for(int mt=0;mt<4;mt++) c2[mt] = (f32x4)(0.f);
    #pragma unroll
    for(int mt=0;mt<4;mt++)
      #pragma unroll
      for(int ks=0;ks<2;ks++){
        f16x8 a = *(const f16x8*)(&Ag[mt*16+n16][ks*32+quad*8]);
        c2[mt] = MFMA16(a, bg2[ks], c2[mt]);
      }
    float s2 = shg2[col];
    #pragma unroll
    for(int mt=0;mt<4;mt++)
      #pragma unroll
      for(int r=0;r<4;r++)
        h_geom[(size_t)(v0 + mt*16+quad*4+r)*64 + col] = (f16)(c2[mt][r] + s2);
    return;
  }

  // ======== chem path: 128 edges ========
  const long p0 = (long)(blockIdx.x - 1024)*128;

  if(t<128) vid_s[t] = svid[p0+t];

  // layer-1 B fragments (held across both row-halves)
  f16x8 b1[2][2];
  #pragma unroll
  for(int p=0;p<2;p++){
    int col = (2*w+p)*16 + n16;
    #pragma unroll
    for(int ks=0;ks<2;ks++)
      b1[p][ks] = *(const f16x8*)(w1f + (size_t)col*64 + ks*32 + quad*8);
  }
  float sh1v[2] = { shift1[(2*w+0)*16+n16], shift1[(2*w+1)*16+n16] };

  // layer 1 over two 64-row halves (keeps accumulator pressure at 4x2 f32x4)
  #pragma unroll
  for(int h=0; h<2; ++h){
    int pe[4];
    #pragma unroll
    for(int mt=0;mt<4;mt++) pe[mt] = perm[p0 + h*64 + mt*16 + n16];

    f32x4 c1[4][2];
    #pragma unroll
    for(int mt=0;mt<4;mt++){ c1[mt][0]=(f32x4)(0.f); c1[mt][1]=(f32x4)(0.f); }
    #pragma unroll
    for(int mt=0;mt<4;mt++){
      const float* base = chem + (size_t)pe[mt]*CI;
      float4 u0 = *(const float4*)(base + quad*8 + 0);
      float4 u1 = *(const float4*)(base + quad*8 + 4);
      f16x8 a0;
      a0[0]=(f16)u0.x; a0[1]=(f16)u0.y; a0[2]=(f16)u0.z; a0[3]=(f16)u0.w;
      a0[4]=(f16)u1.x; a0[5]=(f16)u1.y; a0[6]=(f16)u1.z; a0[7]=(f16)u1.w;
      f16x8 a1 = (f16x8)(f16)0.f;
      if(quad==0){
        float2 uT = *(const float2*)(base + 32);
        a1[0]=(f16)uT.x; a1[1]=(f16)uT.y;
      }
      #pragma unroll
      for(int p=0;p<2;p++){
        c1[mt][p] = MFMA16(a0, b1[p][0], c1[mt][p]);
        c1[mt][p] = MFMA16(a1, b1[p][1], c1[mt][p]);
      }
    }
    #pragma unroll
    for(int mt=0;mt<4;mt++)
      #pragma unroll
      for(int p=0;p<2;p++){
        int col = (2*w+p)*16 + n16;
        #pragma unroll
        for(int r=0;r<4;r++)
          A2[h*64 + mt*16+quad*4+r][col] = (f16)siluf_(c1[mt][p][r] + sh1v[p]);
      }
  }
  __syncthreads();

  // layer 2: two col-group passes; each pass loads its B fragments ONCE and sweeps both halves.
  uint gp0[16], gp1[16];   // [half*8 + mt*2 + j], static indices only
  auto l2pass = [&](const int p, uint* __restrict__ gp){
    const int gf = 2*w + p, gc = gf + 8;
    f16x8 b2f[4], b2c[4];
    #pragma unroll
    for(int ks=0;ks<4;ks++){
      b2f[ks] = *(const f16x8*)(w2f + (size_t)(gf*16+n16)*128 + ks*32 + quad*8);
      b2c[ks] = *(const f16x8*)(w2f + (size_t)(gc*16+n16)*128 + ks*32 + quad*8);
    }
    float shf = shift2[gf*16+n16];
    float shc = shift2[128 + gf*16+n16];
    #pragma unroll
    for(int h=0; h<2; ++h){
      f32x4 cf[4], cc_[4];
      #pragma unroll
      for(int mt=0;mt<4;mt++){ cf[mt]=(f32x4)(0.f); cc_[mt]=(f32x4)(0.f); }
      #pragma unroll
      for(int ks=0;ks<4;ks++){
        f16x8 a[4];
        #pragma unroll
        for(int mt=0;mt<4;mt++)
          a[mt] = *(const f16x8*)(&A2[h*64 + mt*16+n16][ks*32+quad*8]);
        #pragma unroll
        for(int mt=0;mt<4;mt++){
          cf[mt]  = MFMA16(a[mt], b2f[ks], cf[mt]);
          cc_[mt] = MFMA16(a[mt], b2c[ks], cc_[mt]);
        }
      }
      #pragma unroll
      for(int mt=0;mt<4;mt++)
        #pragma unroll
        for(int j=0;j<2;j++){
          float f0 = sigmoidf_(cf[mt][2*j]  +shf);
          float s0 = softplusf_(cc_[mt][2*j]  +shc);
          float f1 = sigmoidf_(cf[mt][2*j+1]+shf);
          float s1 = softplusf_(cc_[mt][2*j+1]+shc);
          union{uint u; f16 h[2];} q;
          q.h[0]=(f16)(f0*s0); q.h[1]=(f16)(f1*s1);
          gp[h*8 + mt*2+j] = q.u;
        }
    }
  };
  l2pass(0, gp0);
  l2pass(1, gp1);
  __syncthreads();                 // all reads of A2 complete

  // write gated values into A2's space (now "G")
  #pragma unroll
  for(int h=0; h<2; ++h)
    #pragma unroll
    for(int mt=0;mt<4;mt++)
      #pragma unroll
      for(int j=0;j<2;j++){
        union{uint u; f16 hh[2];} q0, q1;
        q0.u = gp0[h*8+mt*2+j]; q1.u = gp1[h*8+mt*2+j];
        int row = h*64 + mt*16+quad*4+2*j;
        A2[row  ][(2*w+0)*16+n16] = q0.hh[0];
        A2[row+1][(2*w+0)*16+n16] = q0.hh[1];
        A2[row  ][(2*w+1)*16+n16] = q1.hh[0];
        A2[row+1][(2*w+1)*16+n16] = q1.hh[1];
      }
  __syncthreads();

  // segmented reduce: wave g handles sorted edges [32g, 32g+32); lane l owns cols 2l, 2l+1.
  {
    const int l = lane, g = w;
    const int e_beg = g*32, e_end = e_beg+32;
    float a0=0.f, a1=0.f;
    int cur = vid_s[e_beg];
    #pragma unroll 1
    for(int e=e_beg; e<e_end; ++e){
      int v = vid_s[e];                 // LDS broadcast; branch is wave-uniform
      if(v != cur){
        unsafeAtomicAdd(h_chem + (size_t)cur*H_DIM + 2*l,     a0);
        unsafeAtomicAdd(h_chem + (size_t)cur*H_DIM + 2*l + 1, a1);
        a0=0.f; a1=0.f; cur=v;
      }
      union{uint u; f16 h[2];} q;
      q.u = *(const uint*)&A2[e][2*l];
      a0 += (float)q.h[0]; a1 += (float)q.h[1];
    }
    unsafeAtomicAdd(h_chem + (size_t)cur*H_DIM + 2*l,     a0);
    unsafeAtomicAdd(h_chem + (size_t)cur*H_DIM + 2*l + 1, a1);
  }
}

// ---------------- fallback chem: unsorted, per-element atomics (small ws)
__global__ __launch_bounds__(256) void chem_atomic(
    const float* __restrict__ chem, const int* __restrict__ vids,
    const f16* __restrict__ w1f, const float* __restrict__ shift1,
    const f16* __restrict__ w2f, const float* __restrict__ shift2,
    float* __restrict__ h_chem)
{
  __shared__ __align__(16) f16 A2[64][136];
  __shared__ __align__(16) int vid_s[64];
  const int t = threadIdx.x, w = t>>6, lane = t&63, n16 = lane&15, quad = lane>>4;
  const long e0 = (long)blockIdx.x*64;

  if(t<64) vid_s[t] = vids[e0+t];

  f16x8 b1[2][2];
  #pragma unroll
  for(int p=0;p<2;p++){
    int col = (2*w+p)*16 + n16;
    #pragma unroll
    for(int ks=0;ks<2;ks++)
      b1[p][ks] = *(const f16x8*)(w1f + (size_t)col*64 + ks*32 + quad*8);
  }
  float sh1v[2] = { shift1[(2*w+0)*16+n16], shift1[(2*w+1)*16+n16] };

  f32x4 c1[4][2];
  #pragma unroll
  for(int mt=0;mt<4;mt++){ c1[mt][0]=(f32x4)(0.f); c1[mt][1]=(f32x4)(0.f); }
  #pragma unroll
  for(int mt=0;mt<4;mt++){
    const float* base = chem + (size_t)(e0 + mt*16 + n16)*CI;
    float4 u0 = *(const float4*)(base + quad*8 + 0);
    float4 u1 = *(const float4*)(base + quad*8 + 4);
    f16x8 a0;
    a0[0]=(f16)u0.x; a0[1]=(f16)u0.y; a0[2]=(f16)u0.z; a0[3]=(f16)u0.w;
    a0[4]=(f16)u1.x; a0[5]=(f16)u1.y; a0[6]=(f16)u1.z; a0[7]=(f16)u1.w;
    f16x8 a1 = (f16x8)(f16)0.f;
    if(quad==0){
      float2 uT = *(const float2*)(base + 32);
      a1[0]=(f16)uT.x; a1[1]=(f16)uT.y;
    }
    #pragma unroll
    for(int p=0;p<2;p++){
      c1[mt][p] = MFMA16(a0, b1[p][0], c1[mt][p]);
      c1[mt][p] = MFMA16(a1, b1[p][1], c1[mt][p]);
    }
  }
  #pragma unroll
  for(int mt=0;mt<4;mt++)
    #pragma unroll
    for(int p=0;p<2;p++){
      int col = (2*w+p)*16 + n16;
      #pragma unroll
      for(int r=0;r<4;r++)
        A2[mt*16+quad*4+r][col] = (f16)siluf_(c1[mt][p][r] + sh1v[p]);
    }
  const int ntab[4] = {2*w, 2*w+1, 2*w+8, 2*w+9};
  f16x8 b2[4][4];
  #pragma unroll
  for(int p=0;p<4;p++){
    int col = ntab[p]*16 + n16;
    #pragma unroll
    for(int ks=0;ks<4;ks++)
      b2[p][ks] = *(const f16x8*)(w2f + (size_t)col*128 + ks*32 + quad*8);
  }
  float shf[2] = { shift2[(2*w+0)*16+n16], shift2[(2*w+1)*16+n16] };
  float shc[2] = { shift2[128+(2*w+0)*16+n16], shift2[128+(2*w+1)*16+n16] };
  __syncthreads();

  f32x4 c2[4][4];
  #pragma unroll
  for(int mt=0;mt<4;mt++)
    #pragma unroll
    for(int p=0;p<4;p++) c2[mt][p] = (f32x4)(0.f);
  #pragma unroll
  for(int ks=0;ks<4;ks++){
    f16x8 a[4];
    #pragma unroll
    for(int mt=0;mt<4;mt++)
      a[mt] = *(const f16x8*)(&A2[mt*16+n16][ks*32+quad*8]);
    #pragma unroll
    for(int mt=0;mt<4;mt++)
      #pragma unroll
      for(int p=0;p<4;p++)
        c2[mt][p] = MFMA16(a[mt], b2[p][ks], c2[mt][p]);
  }
  #pragma unroll
  for(int mt=0;mt<4;mt++){
    int4 ev = *(const int4*)&vid_s[mt*16 + quad*4];
    int evv[4] = {ev.x, ev.y, ev.z, ev.w};
    #pragma unroll
    for(int p=0;p<2;p++){
      int colf = (2*w+p)*16 + n16;
      #pragma unroll
      for(int r=0;r<4;r++){
        float f  = sigmoidf_(c2[mt][p][r]   + shf[p]);
        float cc = softplusf_(c2[mt][p+2][r] + shc[p]);
        unsafeAtomicAdd(h_chem + (size_t)evv[r]*H_DIM + colf, f*cc);
      }
    }
  }
}

// ---------------- feat MLP: h_chem fp32 [V][128] + h_geom f16 [V][64] -> out [V][128] f32
__global__ __launch_bounds__(256) void feat_split(
    const float* __restrict__ h_chem, const f16* __restrict__ h_geom,
    const f16* __restrict__ wf1f, const float* __restrict__ shf1,
    const f16* __restrict__ wf2f, const float* __restrict__ shf2,
    float* __restrict__ out)
{
  __shared__ __align__(16) f16 Af[64][200];
  const int t = threadIdx.x, w = t>>6, lane = t&63, n16 = lane&15, quad = lane>>4;
  const int v0 = blockIdx.x*64;

  for(int i=t;i<64*128;i+=256){ int r=i>>7, k=i&127; Af[r][k] = (f16)h_chem[(size_t)(v0+r)*128 + k]; }
  for(int i=t;i<64*64;i+=256){ int r=i>>6, k=i&63; Af[r][128+k] = h_geom[(size_t)(v0+r)*64 + k]; }

  f16x8 B1[2][6];
  #pragma unroll
  for(int p=0;p<2;p++){
    int col = (2*w+p)*16 + n16;
    #pragma unroll
    for(int ks=0;ks<6;ks++)
      B1[p][ks] = *(const f16x8*)(wf1f + (size_t)col*192 + ks*32 + quad*8);
  }
  __syncthreads();

  f32x4 c1[4][2];
  #pragma unroll
  for(int mt=0;mt<4;mt++){ c1[mt][0]=(f32x4)(0.f); c1[mt][1]=(f32x4)(0.f); }
  #pragma unroll
  for(int ks=0;ks<6;ks++){
    f16x8 a[4];
    #pragma unroll
    for(int mt=0;mt<4;mt++)
      a[mt] = *(const f16x8*)(&Af[mt*16+n16][ks*32+quad*8]);
    #pragma unroll
    for(int mt=0;mt<4;mt++)
      #pragma unroll
      for(int p=0;p<2;p++) c1[mt][p] = MFMA16(a[mt], B1[p][ks], c1[mt][p]);
  }
  __syncthreads();

  float s1v[2] = { shf1[(2*w+0)*16+n16], shf1[(2*w+1)*16+n16] };
  #pragma unroll
  for(int mt=0;mt<4;mt++)
    #pragma unroll
    for(int p=0;p<2;p++){
      int col = (2*w+p)*16 + n16;
      #pragma unroll
      for(int r=0;r<4;r++)
        Af[mt*16+quad*4+r][col] = (f16)siluf_(c1[mt][p][r] + s1v[p]);
    }
  __syncthreads();

  f16x8 B2[2][4];
  #pragma unroll
  for(int p=0;p<2;p++){
    int col = (2*w+p)*16 + n16;
    #pragma unroll
    for(int ks=0;ks<4;ks++)
      B2[p][ks] = *(const f16x8*)(wf2f + (size_t)col*128 + ks*32 + quad*8);
  }
  f32x4 c2[4][2];
  #pragma unroll
  for(int mt=0;mt<4;mt++){ c2[mt][0]=(f32x4)(0.f); c2[mt][1]=(f32x4)(0.f); }
  #pragma unroll
  for(int ks=0;ks<4;ks++){
    f16x8 a[4];
    #pragma unroll
    for(int mt=0;mt<4;mt++)
      a[mt] = *(const f16x8*)(&Af[mt*16+n16][ks*32+quad*8]);
    #pragma unroll
    for(int mt=0;mt<4;mt++)
      #pragma unroll
      for(int p=0;p<2;p++) c2[mt][p] = MFMA16(a[mt], B2[p][ks], c2[mt][p]);
  }
  float s2v[2] = { shf2[(2*w+0)*16+n16], shf2[(2*w+1)*16+n16] };
  #pragma unroll
  for(int mt=0;mt<4;mt++)
    #pragma unroll
    for(int p=0;p<2;p++){
      int col = (2*w+p)*16 + n16;
      #pragma unroll
      for(int r=0;r<4;r++)
        out[(size_t)(v0 + mt*16+quad*4+r)*128 + col] = c2[mt][p][r] + s2v[p];
    }
}

extern "C" void kernel_launch(void* const* d_in, const int* in_sizes, int n_in,
                              void* d_out, int out_size, void* d_ws, size_t ws_size,
                              hipStream_t stream) {
  const float* chem = (const float*)d_in[0];
  const float* geom = (const float*)d_in[1];
  const int*   vids = (const int*)d_in[2];
  const float* w1  = (const float*)d_in[3];
  const float* b1  = (const float*)d_in[4];
  const float* bn1 = (const float*)d_in[5];
  const float* w2  = (const float*)d_in[6];
  const float* b2  = (const float*)d_in[7];
  const float* bn2 = (const float*)d_in[8];
  const float* wg1 = (const float*)d_in[9];
  const float* bg1 = (const float*)d_in[10];
  const float* bng1= (const float*)d_in[11];
  const float* wg2 = (const float*)d_in[12];
  const float* bg2 = (const float*)d_in[13];
  const float* bng2= (const float*)d_in[14];
  const float* wf1 = (const float*)d_in[15];
  const float* bf1 = (const float*)d_in[16];
  const float* bnf1= (const float*)d_in[17];
  const float* wf2 = (const float*)d_in[18];
  const float* bf2 = (const float*)d_in[19];
  const float* bnf2= (const float*)d_in[20];
  float* out = (float*)d_out;
  char* ws = (char*)d_ws;

  const size_t NEED_BIG = 51039232ULL;  // h_chem 32M + h_geom 8M + perm 4M + svid 4M + sort 512K + weights
  const bool big = (ws_size >= NEED_BIG);

  if (big) {
    float* h_chem     = (float*)(ws + 0);              // 33554432
    f16*   h_geom     = (f16*)  (ws + 33554432);       // 8388608
    int*   perm       = (int*)  (ws + 41943040);       // 4194304
    int*   svid       = (int*)  (ws + 46137344);       // 4194304
    int*   counts     = (int*)  (ws + 50331648);       // 262144
    int*   offsets_wk = (int*)  (ws + 50593792);       // 262144
    char*  wb         = ws + 50855936;
    f16*   w1f  = (f16*)(wb);            // 16384
    f16*   w2f  = (f16*)(wb + 16384);    // 65536
    f16*   wg1f = (f16*)(wb + 81920);    // 8192
    f16*   wg2f = (f16*)(wb + 90112);    // 8192
    f16*   wf1f = (f16*)(wb + 98304);    // 49152
    f16*   wf2f = (f16*)(wb + 147456);   // 32768
    float* shift1  = (float*)(wb + 180224);
    float* shift2  = (float*)(wb + 180736);
    float* shiftg1 = (float*)(wb + 181760);
    float* shiftg2 = (float*)(wb + 182016);
    float* shiftf1 = (float*)(wb + 182272);
    float* shiftf2 = (float*)(wb + 182784);

    hipMemsetAsync(counts, 0, 65536*sizeof(int), stream);
    front_kernel<<<dim3(3200), dim3(256), 0, stream>>>(
        w1,b1,bn1, w2,b2,bn2, wg1,bg1,bng1, wg2,bg2,bng2, wf1,bf1,bnf1, wf2,bf2,bnf2,
        w1f,shift1, w2f,shift2, wg1f,shiftg1, wg2f,shiftg2, wf1f,shiftf1, wf2f,shiftf2,
        vids, counts, (float4*)h_chem);
    scan_kernel<<<dim3(1), dim3(1024), 0, stream>>>(counts, offsets_wk);
    scatter_kernel<<<dim3(1024), dim3(256), 0, stream>>>(vids, offsets_wk, perm, svid);
    chem_geom<<<dim3(1024 + E_CNT/128), dim3(256), 0, stream>>>(chem, geom, perm, svid,
        w1f,shift1, w2f,shift2, wg1f,shiftg1, wg2f,shiftg2, h_chem, h_geom);
    feat_split<<<dim3(V_CNT/64), dim3(256), 0, stream>>>(h_chem, h_geom, wf1f,shiftf1, wf2f,shiftf2, out);
  } else {
    float* h_chem = (float*)(ws + 0);            // 33554432
    f16*   h_geom = (f16*)  (ws + 33554432);     // 8388608
    char*  wb     = ws + 41943040;
    f16*   w1f  = (f16*)(wb);
    f16*   w2f  = (f16*)(wb + 16384);
    f16*   wg1f = (f16*)(wb + 81920);
    f16*   wg2f = (f16*)(wb + 90112);
    f16*   wf1f = (f16*)(wb + 98304);
    f16*   wf2f = (f16*)(wb + 147456);
    float* shift1  = (float*)(wb + 180224);
    float* shift2  = (float*)(wb + 180736);
    float* shiftg1 = (float*)(wb + 181760);
    float* shiftg2 = (float*)(wb + 182016);
    float* shiftf1 = (float*)(wb + 182272);
    float* shiftf2 = (float*)(wb + 182784);

    hipMemsetAsync(h_chem, 0, (size_t)V_CNT*H_DIM*sizeof(float), stream);
    front_kernel<<<dim3(128), dim3(256), 0, stream>>>(
        w1,b1,bn1, w2,b2,bn2, wg1,bg1,bng1, wg2,bg2,bng2, wf1,bf1,bnf1, wf2,bf2,bnf2,
        w1f,shift1, w2f,shift2, wg1f,shiftg1, wg2f,shiftg2, wf1f,shiftf1, wf2f,shiftf2,
        vids, nullptr, nullptr);
    geom_mfma<<<dim3(V_CNT/64), dim3(256), 0, stream>>>(geom, wg1f,shiftg1, wg2f,shiftg2, h_geom);
    chem_atomic<<<dim3(E_CNT/64), dim3(256), 0, stream>>>(chem, vids, w1f,shift1, w2f,shift2, h_chem);
    feat_split<<<dim3(V_CNT/64), dim3(256), 0, stream>>>(h_chem, h_geom, wf1f,shiftf1, wf2f,shiftf2, out);
  }
}

// Round 5
// 673.808 us; speedup vs baseline: 1.3190x; 1.3190x over previous
//
#include <hip/hip_runtime.h>
#include <cstddef>

constexpr int V_CNT = 65536;
constexpr int E_CNT = 1048576;
constexpr int H_DIM = 128;
constexpr int CI = 34;   // chem in
constexpr int GI = 48;   // geom in
#define EPSF 1e-5f

typedef _Float16 f16;
typedef f16 f16x8 __attribute__((ext_vector_type(8)));
typedef float f32x4 __attribute__((ext_vector_type(4)));
#define MFMA16(a,b,c) __builtin_amdgcn_mfma_f32_16x16x32_f16(a,b,c,0,0,0)

// fast rcp: single v_rcp_f32 (~1ulp) instead of IEEE div sequence
__device__ __forceinline__ float frcp_(float x){ return __builtin_amdgcn_rcpf(x); }
__device__ __forceinline__ float sigmoidf_(float x){ return frcp_(1.0f+__expf(-x)); }
__device__ __forceinline__ float siluf_(float x){ return x*frcp_(1.0f+__expf(-x)); }
__device__ __forceinline__ float softplusf_(float x){
  return fmaxf(x,0.0f) + __logf(1.0f + __expf(-fabsf(x)));
}

// ---------------- FRONT: prep (blocks 0..127) + hist (blocks 128..1151) + zero h_chem (1152..3199)
__global__ __launch_bounds__(256) void front_kernel(
    const float* __restrict__ w1, const float* __restrict__ b1, const float* __restrict__ bn1,
    const float* __restrict__ w2, const float* __restrict__ b2, const float* __restrict__ bn2,
    const float* __restrict__ wg1, const float* __restrict__ bg1, const float* __restrict__ bng1,
    const float* __restrict__ wg2, const float* __restrict__ bg2, const float* __restrict__ bng2,
    const float* __restrict__ wf1, const float* __restrict__ bf1, const float* __restrict__ bnf1,
    const float* __restrict__ wf2, const float* __restrict__ bf2, const float* __restrict__ bnf2,
    f16* __restrict__ w1f, float* __restrict__ shift1,
    f16* __restrict__ w2f, float* __restrict__ shift2,
    f16* __restrict__ wg1f, float* __restrict__ shiftg1,
    f16* __restrict__ wg2f, float* __restrict__ shiftg2,
    f16* __restrict__ wf1f, float* __restrict__ shiftf1,
    f16* __restrict__ wf2f, float* __restrict__ shiftf2,
    const int* __restrict__ vids, int* __restrict__ counts,
    float4* __restrict__ h_chem_zero)
{
  const int b = blockIdx.x;
  if (b >= 1152) {                      // zero h_chem: 2048 blocks
    int i = (b-1152)*256 + threadIdx.x;
    float4 z; z.x=0.f; z.y=0.f; z.z=0.f; z.w=0.f;
    const int n4 = V_CNT*H_DIM/4;
    for(; i<n4; i+=2048*256) h_chem_zero[i] = z;
    return;
  }
  if (b >= 128) {                       // hist: 1024 blocks
    int i = (b-128)*256 + threadIdx.x;
    for(; i<E_CNT; i+=1024*256) atomicAdd(&counts[vids[i]], 1);
    return;
  }
  int t = b*256 + threadIdx.x;
  if (t < 128*64){                       // chem L1: [128 cols][64 k], k>=34 zero
    int n = t>>6, k = t&63;
    float s = bn1[n]*rsqrtf(bn1[384+n]+EPSF);
    w1f[t] = (k<CI) ? (f16)(w1[k*128+n]*s) : (f16)0.f;
    if (k==0) shift1[n] = fmaf(s, b1[n]-bn1[256+n], bn1[128+n]);
  }
  if (t < 256*128){                      // chem L2: [256 cols][128 k]
    int n = t>>7, k = t&127;
    float s = bn2[n]*rsqrtf(bn2[768+n]+EPSF);
    w2f[t] = (f16)(w2[k*256+n]*s);
    if (k==0) shift2[n] = fmaf(s, b2[n]-bn2[512+n], bn2[256+n]);
  }
  if (t < 64*64){                        // geom L1: [64 cols][64 k], k>=48 zero
    int n = t>>6, k = t&63;
    float s = bng1[n]*rsqrtf(bng1[192+n]+EPSF);
    wg1f[t] = (k<GI) ? (f16)(wg1[k*64+n]*s) : (f16)0.f;
    if (k==0) shiftg1[n] = fmaf(s, bg1[n]-bng1[128+n], bng1[64+n]);
  }
  if (t < 64*64){                        // geom L2: [64 cols][64 k]
    int n = t>>6, k = t&63;
    float s = bng2[n]*rsqrtf(bng2[192+n]+EPSF);
    wg2f[t] = (f16)(wg2[k*64+n]*s);
    if (k==0) shiftg2[n] = fmaf(s, bg2[n]-bng2[128+n], bng2[64+n]);
  }
  if (t < 128*192){                      // feat L1: [128 cols][192 k]
    int n = t/192, k = t - n*192;
    float s = bnf1[n]*rsqrtf(bnf1[384+n]+EPSF);
    wf1f[t] = (f16)(wf1[k*128+n]*s);
    if (k==0) shiftf1[n] = fmaf(s, bf1[n]-bnf1[256+n], bnf1[128+n]);
  }
  if (t < 128*128){                      // feat L2: [128 cols][128 k]
    int n = t>>7, k = t&127;
    float s = bnf2[n]*rsqrtf(bnf2[384+n]+EPSF);
    wf2f[t] = (f16)(wf2[k*128+n]*s);
    if (k==0) shiftf2[n] = fmaf(s, bf2[n]-bnf2[256+n], bnf2[128+n]);
  }
}

__global__ __launch_bounds__(1024) void scan_kernel(const int* __restrict__ counts,
                                                    int* __restrict__ offsets_work){
  __shared__ int ps[1024];
  const int t = threadIdx.x;
  int4 c[16]; int s = 0;
  const int4* cp = (const int4*)counts + (size_t)t*16;
  #pragma unroll
  for(int i=0;i<16;i++){ c[i]=cp[i]; s += c[i].x+c[i].y+c[i].z+c[i].w; }
  ps[t]=s; __syncthreads();
  for(int d=1; d<1024; d<<=1){
    int v = (t>=d) ? ps[t-d] : 0;
    __syncthreads();
    ps[t] += v;
    __syncthreads();
  }
  int run = ps[t]-s;
  int4* o2 = (int4*)offsets_work + (size_t)t*16;
  #pragma unroll
  for(int i=0;i<16;i++){
    int4 cc=c[i]; int4 o;
    o.x=run; run+=cc.x; o.y=run; run+=cc.y; o.z=run; run+=cc.z; o.w=run; run+=cc.w;
    o2[i]=o;
  }
}

// ---------------- SCATTER+GEOM co-launch:
// blocks [0,1024): scatter edges -> epair[pos]=(edge, vid) as ONE 8B store (halves dirty lines)
// blocks [1024,2048): geom MLP (independent of sort chain; MFMA-bound work hides under scatter)
__global__ __launch_bounds__(256) void scatter_geom(
    const int* __restrict__ vids, int* __restrict__ offsets_work, int2* __restrict__ epair,
    const float* __restrict__ geom,
    const f16* __restrict__ wg1f, const float* __restrict__ shg1,
    const f16* __restrict__ wg2f, const float* __restrict__ shg2,
    f16* __restrict__ h_geom)
{
  __shared__ __align__(16) f16 Ag[64][72];
  const int t = threadIdx.x;

  if (blockIdx.x < 1024) {
    int i = blockIdx.x*256 + t;
    for(; i<E_CNT; i+=1024*256){
      int v = vids[i];
      int pos = atomicAdd(&offsets_work[v], 1);
      epair[pos] = make_int2(i, v);
    }
    return;
  }

  // ======== geom path ========
  const int w = t>>6, lane = t&63, n16 = lane&15, quad = lane>>4;
  const int v0 = (blockIdx.x-1024)*64;
  const int col = w*16 + n16;

  for(int i=t;i<64*GI;i+=256){ int r=i/GI, k=i-r*GI; Ag[r][k] = (f16)geom[(size_t)v0*GI + i]; }
  { uint* Aw=(uint*)&Ag[0][0]; for(int i=t;i<64*8;i+=256){ int r=i>>3; Aw[r*36+24+(i&7)]=0u; } }

  f16x8 bg1[2], bg2[2];
  #pragma unroll
  for(int ks=0;ks<2;ks++){
    bg1[ks] = *(const f16x8*)(wg1f + (size_t)col*64 + ks*32 + quad*8);
    bg2[ks] = *(const f16x8*)(wg2f + (size_t)col*64 + ks*32 + quad*8);
  }
  __syncthreads();

  f32x4 c1[4];
  #pragma unroll
  for(int mt=0;mt<4;mt++) c1[mt] = (f32x4)(0.f);
  #pragma unroll
  for(int mt=0;mt<4;mt++)
    #pragma unroll
    for(int ks=0;ks<2;ks++){
      f16x8 a = *(const f16x8*)(&Ag[mt*16+n16][ks*32+quad*8]);
      c1[mt] = MFMA16(a, bg1[ks], c1[mt]);
    }
  __syncthreads();

  float s1 = shg1[col];
  #pragma unroll
  for(int mt=0;mt<4;mt++)
    #pragma unroll
    for(int r=0;r<4;r++)
      Ag[mt*16+quad*4+r][col] = (f16)siluf_(c1[mt][r] + s1);
  __syncthreads();

  f32x4 c2[4];
  #pragma unroll
  for(int mt=0;mt<4;mt++) c2[mt] = (f32x4)(0.f);
  #pragma unroll
  for(int mt=0;mt<4;mt++)
    #pragma unroll
    for(int ks=0;ks<2;ks++){
      f16x8 a = *(const f16x8*)(&Ag[mt*16+n16][ks*32+quad*8]);
      c2[mt] = MFMA16(a, bg2[ks], c2[mt]);
    }
  float s2 = shg2[col];
  #pragma unroll
  for(int mt=0;mt<4;mt++)
    #pragma unroll
    for(int r=0;r<4;r++)
      h_geom[(size_t)(v0 + mt*16+quad*4+r)*64 + col] = (f16)(c2[mt][r] + s2);
}

// ---------------- geom MLP standalone (fallback path only)
__global__ __launch_bounds__(256) void geom_mfma(
    const float* __restrict__ geom,
    const f16* __restrict__ wg1f, const float* __restrict__ shg1,
    const f16* __restrict__ wg2f, const float* __restrict__ shg2,
    f16* __restrict__ dst)
{
  __shared__ __align__(16) f16 Ag[64][72];
  const int t = threadIdx.x, w = t>>6, lane = t&63, n16 = lane&15, quad = lane>>4;
  const int v0 = blockIdx.x*64;
  const int col = w*16 + n16;

  for(int i=t;i<64*GI;i+=256){ int r=i/GI, k=i-r*GI; Ag[r][k] = (f16)geom[(size_t)v0*GI + i]; }
  { uint* Aw=(uint*)Ag; for(int i=t;i<64*8;i+=256){ int r=i>>3; Aw[r*36+24+(i&7)]=0u; } }

  f16x8 bg1[2], bg2[2];
  #pragma unroll
  for(int ks=0;ks<2;ks++){
    bg1[ks] = *(const f16x8*)(wg1f + (size_t)col*64 + ks*32 + quad*8);
    bg2[ks] = *(const f16x8*)(wg2f + (size_t)col*64 + ks*32 + quad*8);
  }
  __syncthreads();

  f32x4 c1[4];
  #pragma unroll
  for(int mt=0;mt<4;mt++) c1[mt] = (f32x4)(0.f);
  #pragma unroll
  for(int mt=0;mt<4;mt++)
    #pragma unroll
    for(int ks=0;ks<2;ks++){
      f16x8 a = *(const f16x8*)(&Ag[mt*16+n16][ks*32+quad*8]);
      c1[mt] = MFMA16(a, bg1[ks], c1[mt]);
    }
  __syncthreads();

  float s1 = shg1[col];
  #pragma unroll
  for(int mt=0;mt<4;mt++)
    #pragma unroll
    for(int r=0;r<4;r++)
      Ag[mt*16+quad*4+r][col] = (f16)siluf_(c1[mt][r] + s1);
  __syncthreads();

  f32x4 c2[4];
  #pragma unroll
  for(int mt=0;mt<4;mt++) c2[mt] = (f32x4)(0.f);
  #pragma unroll
  for(int mt=0;mt<4;mt++)
    #pragma unroll
    for(int ks=0;ks<2;ks++){
      f16x8 a = *(const f16x8*)(&Ag[mt*16+n16][ks*32+quad*8]);
      c2[mt] = MFMA16(a, bg2[ks], c2[mt]);
    }
  float s2 = shg2[col];
  #pragma unroll
  for(int mt=0;mt<4;mt++)
    #pragma unroll
    for(int r=0;r<4;r++)
      dst[(size_t)(v0 + mt*16+quad*4+r)*64 + col] = (f16)(c2[mt][r] + s2);
}

// ---------------- FUSED chem (proven R2 config): 64 sorted edges/block, VGPR~76, LDS 17.9K.
// Sorted-gather chem MLP + gate + in-block segmented reduce -> h_chem (f32).
__global__ __launch_bounds__(256) void chem_fused(
    const float* __restrict__ chem,
    const int2* __restrict__ epair,
    const f16* __restrict__ w1f, const float* __restrict__ shift1,
    const f16* __restrict__ w2f, const float* __restrict__ shift2,
    float* __restrict__ h_chem)
{
  __shared__ __align__(16) f16 A2[64][136];   // L1 activations, later reused as gated G
  __shared__ int vid_s[64];
  const int t = threadIdx.x, w = t>>6, lane = t&63, n16 = lane&15, quad = lane>>4;
  const long p0 = (long)blockIdx.x*64;

  if(t<64) vid_s[t] = epair[p0+t].y;

  // layer-1 B fragments
  f16x8 b1[2][2];
  #pragma unroll
  for(int p=0;p<2;p++){
    int col = (2*w+p)*16 + n16;
    #pragma unroll
    for(int ks=0;ks<2;ks++)
      b1[p][ks] = *(const f16x8*)(w1f + (size_t)col*64 + ks*32 + quad*8);
  }
  float sh1v[2] = { shift1[(2*w+0)*16+n16], shift1[(2*w+1)*16+n16] };

  // gather row indices for this (mt, n16) lane
  int pe[4];
  #pragma unroll
  for(int mt=0;mt<4;mt++) pe[mt] = epair[p0 + mt*16 + n16].x;

  // layer 1: A fragments gathered from global (row-major fp32 -> f16 regs)
  f32x4 c1[4][2];
  #pragma unroll
  for(int mt=0;mt<4;mt++){ c1[mt][0]=(f32x4)(0.f); c1[mt][1]=(f32x4)(0.f); }
  #pragma unroll
  for(int mt=0;mt<4;mt++){
    const float* base = chem + (size_t)pe[mt]*CI;
    float4 u0 = *(const float4*)(base + quad*8 + 0);
    float4 u1 = *(const float4*)(base + quad*8 + 4);
    f16x8 a0;
    a0[0]=(f16)u0.x; a0[1]=(f16)u0.y; a0[2]=(f16)u0.z; a0[3]=(f16)u0.w;
    a0[4]=(f16)u1.x; a0[5]=(f16)u1.y; a0[6]=(f16)u1.z; a0[7]=(f16)u1.w;
    f16x8 a1 = (f16x8)(f16)0.f;
    if(quad==0){
      float2 uT = *(const float2*)(base + 32);
      a1[0]=(f16)uT.x; a1[1]=(f16)uT.y;
    }
    #pragma unroll
    for(int p=0;p<2;p++){
      c1[mt][p] = MFMA16(a0, b1[p][0], c1[mt][p]);
      c1[mt][p] = MFMA16(a1, b1[p][1], c1[mt][p]);
    }
  }
  // activation -> A2 (transpose C->A layout via LDS)
  #pragma unroll
  for(int mt=0;mt<4;mt++)
    #pragma unroll
    for(int p=0;p<2;p++){
      int col = (2*w+p)*16 + n16;
      #pragma unroll
      for(int r=0;r<4;r++)
        A2[mt*16+quad*4+r][col] = (f16)siluf_(c1[mt][p][r] + sh1v[p]);
    }
  __syncthreads();

  // layer 2 in two peeled passes; gated results stay packed in regs (8 u32 each).
  uint gp0[8], gp1[8];
  auto l2pass = [&](const int p, uint* __restrict__ gp){
    const int gf = 2*w + p, gc = gf + 8;
    f16x8 b2f[4], b2c[4];
    #pragma unroll
    for(int ks=0;ks<4;ks++){
      b2f[ks] = *(const f16x8*)(w2f + (size_t)(gf*16+n16)*128 + ks*32 + quad*8);
      b2c[ks] = *(const f16x8*)(w2f + (size_t)(gc*16+n16)*128 + ks*32 + quad*8);
    }
    float shf = shift2[gf*16+n16];
    float shc = shift2[128 + gf*16+n16];
    f32x4 cf[4], cc_[4];
    #pragma unroll
    for(int mt=0;mt<4;mt++){ cf[mt]=(f32x4)(0.f); cc_[mt]=(f32x4)(0.f); }
    #pragma unroll
    for(int ks=0;ks<4;ks++){
      f16x8 a[4];
      #pragma unroll
      for(int mt=0;mt<4;mt++)
        a[mt] = *(const f16x8*)(&A2[mt*16+n16][ks*32+quad*8]);
      #pragma unroll
      for(int mt=0;mt<4;mt++){
        cf[mt]  = MFMA16(a[mt], b2f[ks], cf[mt]);
        cc_[mt] = MFMA16(a[mt], b2c[ks], cc_[mt]);
      }
    }
    #pragma unroll
    for(int mt=0;mt<4;mt++)
      #pragma unroll
      for(int j=0;j<2;j++){
        float f0 = sigmoidf_(cf[mt][2*j]  +shf);
        float s0 = softplusf_(cc_[mt][2*j]  +shc);
        float f1 = sigmoidf_(cf[mt][2*j+1]+shf);
        float s1 = softplusf_(cc_[mt][2*j+1]+shc);
        union{uint u; f16 h[2];} q;
        q.h[0]=(f16)(f0*s0); q.h[1]=(f16)(f1*s1);
        gp[mt*2+j] = q.u;
      }
  };
  l2pass(0, gp0);
  l2pass(1, gp1);
  __syncthreads();                 // all reads of A2 complete

  // write gated values into A2's space (now "G")
  #pragma unroll
  for(int mt=0;mt<4;mt++)
    #pragma unroll
    for(int j=0;j<2;j++){
      union{uint u; f16 h[2];} q0, q1;
      q0.u = gp0[mt*2+j]; q1.u = gp1[mt*2+j];
      int row = mt*16+quad*4+2*j;
      A2[row  ][(2*w+0)*16+n16] = q0.h[0];
      A2[row+1][(2*w+0)*16+n16] = q0.h[1];
      A2[row  ][(2*w+1)*16+n16] = q1.h[0];
      A2[row+1][(2*w+1)*16+n16] = q1.h[1];
    }
  __syncthreads();

  // segmented reduce: wave g handles sorted edges [16g, 16g+16); lane l owns cols 2l, 2l+1.
  {
    const int l = lane, g = w;
    const int e_beg = g*16, e_end = e_beg+16;
    float a0=0.f, a1=0.f;
    int cur = vid_s[e_beg];
    #pragma unroll 1
    for(int e=e_beg; e<e_end; ++e){
      int v = vid_s[e];                 // LDS broadcast; branch is wave-uniform
      if(v != cur){
        unsafeAtomicAdd(h_chem + (size_t)cur*H_DIM + 2*l,     a0);
        unsafeAtomicAdd(h_chem + (size_t)cur*H_DIM + 2*l + 1, a1);
        a0=0.f; a1=0.f; cur=v;
      }
      union{uint u; f16 h[2];} q;
      q.u = *(const uint*)&A2[e][2*l];
      a0 += (float)q.h[0]; a1 += (float)q.h[1];
    }
    unsafeAtomicAdd(h_chem + (size_t)cur*H_DIM + 2*l,     a0);
    unsafeAtomicAdd(h_chem + (size_t)cur*H_DIM + 2*l + 1, a1);
  }
}

// ---------------- fallback chem: unsorted, per-element atomics (small ws)
__global__ __launch_bounds__(256) void chem_atomic(
    const float* __restrict__ chem, const int* __restrict__ vids,
    const f16* __restrict__ w1f, const float* __restrict__ shift1,
    const f16* __restrict__ w2f, const float* __restrict__ shift2,
    float* __restrict__ h_chem)
{
  __shared__ __align__(16) f16 A2[64][136];
  __shared__ __align__(16) int vid_s[64];
  const int t = threadIdx.x, w = t>>6, lane = t&63, n16 = lane&15, quad = lane>>4;
  const long e0 = (long)blockIdx.x*64;

  if(t<64) vid_s[t] = vids[e0+t];

  f16x8 b1[2][2];
  #pragma unroll
  for(int p=0;p<2;p++){
    int col = (2*w+p)*16 + n16;
    #pragma unroll
    for(int ks=0;ks<2;ks++)
      b1[p][ks] = *(const f16x8*)(w1f + (size_t)col*64 + ks*32 + quad*8);
  }
  float sh1v[2] = { shift1[(2*w+0)*16+n16], shift1[(2*w+1)*16+n16] };

  f32x4 c1[4][2];
  #pragma unroll
  for(int mt=0;mt<4;mt++){ c1[mt][0]=(f32x4)(0.f); c1[mt][1]=(f32x4)(0.f); }
  #pragma unroll
  for(int mt=0;mt<4;mt++){
    const float* base = chem + (size_t)(e0 + mt*16 + n16)*CI;
    float4 u0 = *(const float4*)(base + quad*8 + 0);
    float4 u1 = *(const float4*)(base + quad*8 + 4);
    f16x8 a0;
    a0[0]=(f16)u0.x; a0[1]=(f16)u0.y; a0[2]=(f16)u0.z; a0[3]=(f16)u0.w;
    a0[4]=(f16)u1.x; a0[5]=(f16)u1.y; a0[6]=(f16)u1.z; a0[7]=(f16)u1.w;
    f16x8 a1 = (f16x8)(f16)0.f;
    if(quad==0){
      float2 uT = *(const float2*)(base + 32);
      a1[0]=(f16)uT.x; a1[1]=(f16)uT.y;
    }
    #pragma unroll
    for(int p=0;p<2;p++){
      c1[mt][p] = MFMA16(a0, b1[p][0], c1[mt][p]);
      c1[mt][p] = MFMA16(a1, b1[p][1], c1[mt][p]);
    }
  }
  #pragma unroll
  for(int mt=0;mt<4;mt++)
    #pragma unroll
    for(int p=0;p<2;p++){
      int col = (2*w+p)*16 + n16;
      #pragma unroll
      for(int r=0;r<4;r++)
        A2[mt*16+quad*4+r][col] = (f16)siluf_(c1[mt][p][r] + sh1v[p]);
    }
  const int ntab[4] = {2*w, 2*w+1, 2*w+8, 2*w+9};
  f16x8 b2[4][4];
  #pragma unroll
  for(int p=0;p<4;p++){
    int col = ntab[p]*16 + n16;
    #pragma unroll
    for(int ks=0;ks<4;ks++)
      b2[p][ks] = *(const f16x8*)(w2f + (size_t)col*128 + ks*32 + quad*8);
  }
  float shf[2] = { shift2[(2*w+0)*16+n16], shift2[(2*w+1)*16+n16] };
  float shc[2] = { shift2[128+(2*w+0)*16+n16], shift2[128+(2*w+1)*16+n16] };
  __syncthreads();

  f32x4 c2[4][4];
  #pragma unroll
  for(int mt=0;mt<4;mt++)
    #pragma unroll
    for(int p=0;p<4;p++) c2[mt][p] = (f32x4)(0.f);
  #pragma unroll
  for(int ks=0;ks<4;ks++){
    f16x8 a[4];
    #pragma unroll
    for(int mt=0;mt<4;mt++)
      a[mt] = *(const f16x8*)(&A2[mt*16+n16][ks*32+quad*8]);
    #pragma unroll
    for(int mt=0;mt<4;mt++)
      #pragma unroll
      for(int p=0;p<4;p++)
        c2[mt][p] = MFMA16(a[mt], b2[p][ks], c2[mt][p]);
  }
  #pragma unroll
  for(int mt=0;mt<4;mt++){
    int4 ev = *(const int4*)&vid_s[mt*16 + quad*4];
    int evv[4] = {ev.x, ev.y, ev.z, ev.w};
    #pragma unroll
    for(int p=0;p<2;p++){
      int colf = (2*w+p)*16 + n16;
      #pragma unroll
      for(int r=0;r<4;r++){
        float f  = sigmoidf_(c2[mt][p][r]   + shf[p]);
        float cc = softplusf_(c2[mt][p+2][r] + shc[p]);
        unsafeAtomicAdd(h_chem + (size_t)evv[r]*H_DIM + colf, f*cc);
      }
    }
  }
}

// ---------------- feat MLP: h_chem fp32 [V][128] + h_geom f16 [V][64] -> out [V][128] f32
__global__ __launch_bounds__(256) void feat_split(
    const float* __restrict__ h_chem, const f16* __restrict__ h_geom,
    const f16* __restrict__ wf1f, const float* __restrict__ shf1,
    const f16* __restrict__ wf2f, const float* __restrict__ shf2,
    float* __restrict__ out)
{
  __shared__ __align__(16) f16 Af[64][200];
  const int t = threadIdx.x, w = t>>6, lane = t&63, n16 = lane&15, quad = lane>>4;
  const int v0 = blockIdx.x*64;

  for(int i=t;i<64*128;i+=256){ int r=i>>7, k=i&127; Af[r][k] = (f16)h_chem[(size_t)(v0+r)*128 + k]; }
  for(int i=t;i<64*64;i+=256){ int r=i>>6, k=i&63; Af[r][128+k] = h_geom[(size_t)(v0+r)*64 + k]; }

  f16x8 B1[2][6];
  #pragma unroll
  for(int p=0;p<2;p++){
    int col = (2*w+p)*16 + n16;
    #pragma unroll
    for(int ks=0;ks<6;ks++)
      B1[p][ks] = *(const f16x8*)(wf1f + (size_t)col*192 + ks*32 + quad*8);
  }
  __syncthreads();

  f32x4 c1[4][2];
  #pragma unroll
  for(int mt=0;mt<4;mt++){ c1[mt][0]=(f32x4)(0.f); c1[mt][1]=(f32x4)(0.f); }
  #pragma unroll
  for(int ks=0;ks<6;ks++){
    f16x8 a[4];
    #pragma unroll
    for(int mt=0;mt<4;mt++)
      a[mt] = *(const f16x8*)(&Af[mt*16+n16][ks*32+quad*8]);
    #pragma unroll
    for(int mt=0;mt<4;mt++)
      #pragma unroll
      for(int p=0;p<2;p++) c1[mt][p] = MFMA16(a[mt], B1[p][ks], c1[mt][p]);
  }
  __syncthreads();

  float s1v[2] = { shf1[(2*w+0)*16+n16], shf1[(2*w+1)*16+n16] };
  #pragma unroll
  for(int mt=0;mt<4;mt++)
    #pragma unroll
    for(int p=0;p<2;p++){
      int col = (2*w+p)*16 + n16;
      #pragma unroll
      for(int r=0;r<4;r++)
        Af[mt*16+quad*4+r][col] = (f16)siluf_(c1[mt][p][r] + s1v[p]);
    }
  __syncthreads();

  f16x8 B2[2][4];
  #pragma unroll
  for(int p=0;p<2;p++){
    int col = (2*w+p)*16 + n16;
    #pragma unroll
    for(int ks=0;ks<4;ks++)
      B2[p][ks] = *(const f16x8*)(wf2f + (size_t)col*128 + ks*32 + quad*8);
  }
  f32x4 c2[4][2];
  #pragma unroll
  for(int mt=0;mt<4;mt++){ c2[mt][0]=(f32x4)(0.f); c2[mt][1]=(f32x4)(0.f); }
  #pragma unroll
  for(int ks=0;ks<4;ks++){
    f16x8 a[4];
    #pragma unroll
    for(int mt=0;mt<4;mt++)
      a[mt] = *(const f16x8*)(&Af[mt*16+n16][ks*32+quad*8]);
    #pragma unroll
    for(int mt=0;mt<4;mt++)
      #pragma unroll
      for(int p=0;p<2;p++) c2[mt][p] = MFMA16(a[mt], B2[p][ks], c2[mt][p]);
  }
  float s2v[2] = { shf2[(2*w+0)*16+n16], shf2[(2*w+1)*16+n16] };
  #pragma unroll
  for(int mt=0;mt<4;mt++)
    #pragma unroll
    for(int p=0;p<2;p++){
      int col = (2*w+p)*16 + n16;
      #pragma unroll
      for(int r=0;r<4;r++)
        out[(size_t)(v0 + mt*16+quad*4+r)*128 + col] = c2[mt][p][r] + s2v[p];
    }
}

extern "C" void kernel_launch(void* const* d_in, const int* in_sizes, int n_in,
                              void* d_out, int out_size, void* d_ws, size_t ws_size,
                              hipStream_t stream) {
  const float* chem = (const float*)d_in[0];
  const float* geom = (const float*)d_in[1];
  const int*   vids = (const int*)d_in[2];
  const float* w1  = (const float*)d_in[3];
  const float* b1  = (const float*)d_in[4];
  const float* bn1 = (const float*)d_in[5];
  const float* w2  = (const float*)d_in[6];
  const float* b2  = (const float*)d_in[7];
  const float* bn2 = (const float*)d_in[8];
  const float* wg1 = (const float*)d_in[9];
  const float* bg1 = (const float*)d_in[10];
  const float* bng1= (const float*)d_in[11];
  const float* wg2 = (const float*)d_in[12];
  const float* bg2 = (const float*)d_in[13];
  const float* bng2= (const float*)d_in[14];
  const float* wf1 = (const float*)d_in[15];
  const float* bf1 = (const float*)d_in[16];
  const float* bnf1= (const float*)d_in[17];
  const float* wf2 = (const float*)d_in[18];
  const float* bf2 = (const float*)d_in[19];
  const float* bnf2= (const float*)d_in[20];
  float* out = (float*)d_out;
  char* ws = (char*)d_ws;

  const size_t NEED_BIG = 51039232ULL;  // h_chem 32M + h_geom 8M + epair 8M + sort 512K + weights
  const bool big = (ws_size >= NEED_BIG);

  if (big) {
    float* h_chem     = (float*)(ws + 0);              // 33554432
    f16*   h_geom     = (f16*)  (ws + 33554432);       // 8388608
    int2*  epair      = (int2*) (ws + 41943040);       // 8388608
    int*   counts     = (int*)  (ws + 50331648);       // 262144
    int*   offsets_wk = (int*)  (ws + 50593792);       // 262144
    char*  wb         = ws + 50855936;
    f16*   w1f  = (f16*)(wb);            // 16384
    f16*   w2f  = (f16*)(wb + 16384);    // 65536
    f16*   wg1f = (f16*)(wb + 81920);    // 8192
    f16*   wg2f = (f16*)(wb + 90112);    // 8192
    f16*   wf1f = (f16*)(wb + 98304);    // 49152
    f16*   wf2f = (f16*)(wb + 147456);   // 32768
    float* shift1  = (float*)(wb + 180224);
    float* shift2  = (float*)(wb + 180736);
    float* shiftg1 = (float*)(wb + 181760);
    float* shiftg2 = (float*)(wb + 182016);
    float* shiftf1 = (float*)(wb + 182272);
    float* shiftf2 = (float*)(wb + 182784);

    hipMemsetAsync(counts, 0, 65536*sizeof(int), stream);
    front_kernel<<<dim3(3200), dim3(256), 0, stream>>>(
        w1,b1,bn1, w2,b2,bn2, wg1,bg1,bng1, wg2,bg2,bng2, wf1,bf1,bnf1, wf2,bf2,bnf2,
        w1f,shift1, w2f,shift2, wg1f,shiftg1, wg2f,shiftg2, wf1f,shiftf1, wf2f,shiftf2,
        vids, counts, (float4*)h_chem);
    scan_kernel<<<dim3(1), dim3(1024), 0, stream>>>(counts, offsets_wk);
    scatter_geom<<<dim3(2048), dim3(256), 0, stream>>>(vids, offsets_wk, epair,
        geom, wg1f,shiftg1, wg2f,shiftg2, h_geom);
    chem_fused<<<dim3(E_CNT/64), dim3(256), 0, stream>>>(chem, epair,
        w1f,shift1, w2f,shift2, h_chem);
    feat_split<<<dim3(V_CNT/64), dim3(256), 0, stream>>>(h_chem, h_geom, wf1f,shiftf1, wf2f,shiftf2, out);
  } else {
    float* h_chem = (float*)(ws + 0);            // 33554432
    f16*   h_geom = (f16*)  (ws + 33554432);     // 8388608
    char*  wb     = ws + 41943040;
    f16*   w1f  = (f16*)(wb);
    f16*   w2f  = (f16*)(wb + 16384);
    f16*   wg1f = (f16*)(wb + 81920);
    f16*   wg2f = (f16*)(wb + 90112);
    f16*   wf1f = (f16*)(wb + 98304);
    f16*   wf2f = (f16*)(wb + 147456);
    float* shift1  = (float*)(wb + 180224);
    float* shift2  = (float*)(wb + 180736);
    float* shiftg1 = (float*)(wb + 181760);
    float* shiftg2 = (float*)(wb + 182016);
    float* shiftf1 = (float*)(wb + 182272);
    float* shiftf2 = (float*)(wb + 182784);

    hipMemsetAsync(h_chem, 0, (size_t)V_CNT*H_DIM*sizeof(float), stream);
    front_kernel<<<dim3(128), dim3(256), 0, stream>>>(
        w1,b1,bn1, w2,b2,bn2, wg1,bg1,bng1, wg2,bg2,bng2, wf1,bf1,bnf1, wf2,bf2,bnf2,
        w1f,shift1, w2f,shift2, wg1f,shiftg1, wg2f,shiftg2, wf1f,shiftf1, wf2f,shiftf2,
        vids, nullptr, nullptr);
    geom_mfma<<<dim3(V_CNT/64), dim3(256), 0, stream>>>(geom, wg1f,shiftg1, wg2f,shiftg2, h_geom);
    chem_atomic<<<dim3(E_CNT/64), dim3(256), 0, stream>>>(chem, vids, w1f,shift1, w2f,shift2, h_chem);
    feat_split<<<dim3(V_CNT/64), dim3(256), 0, stream>>>(h_chem, h_geom, wf1f,shiftf1, wf2f,shiftf2, out);
  }
}